// Round 1
// baseline (750.134 us; speedup 1.0000x reference)
//
#include <hip/hip_runtime.h>
#include <math.h>

#define NB 32
#define DD 2048
#define NH 16
#define NKVH 2
#define DHD 128
#define SPAST 8192
#define NREP 8
#define NCHUNK 8
#define CHUNK 1024

// ws layout (float offsets):
// q     : [0, 65536)        [b][h][d]
// k_new : [65536, 73728)    [b][kvh][d]
// v_new : [73728, 81920)    [b][kvh][d]
// attn  : [81920, 147456)   [b][h*dh]
// Opart : [147456, 671744)  [b][h][chunk][d]
// Mpart : [671744, 675840)  [b][h][chunk]
// Lpart : [675840, 679936)  [b][h][chunk]

__global__ __launch_bounds__(256) void zero_kernel(float* ws, float* out) {
    int idx = blockIdx.x * 256 + threadIdx.x;
    if (idx < 81920) ws[idx] = 0.0f;
    if (idx < 65536) out[idx] = 0.0f;
}

// Y[b][n] += sum_k X[b][k] * W[k][n]   (split-K + batch-group via atomics)
// grid: (N/256, B/4, K/512)
__global__ __launch_bounds__(256)
void gemm_atomic(const float* __restrict__ X, const float* __restrict__ W,
                 float* __restrict__ Y, int K, int N) {
    const int KC = 512;
    int col = blockIdx.x * 256 + threadIdx.x;
    int b0  = blockIdx.y * 4;
    int k0  = blockIdx.z * KC;
    __shared__ __align__(16) float xs[512][4];
    for (int i = threadIdx.x; i < KC * 4; i += 256) {
        int bb = i >> 9;          // 0..3
        int kk = i & 511;         // coalesced over kk
        xs[kk][bb] = X[(size_t)(b0 + bb) * K + k0 + kk];
    }
    __syncthreads();
    float a0 = 0.f, a1 = 0.f, a2 = 0.f, a3 = 0.f;
    const float* wp = W + (size_t)k0 * N + col;
    #pragma unroll 8
    for (int kk = 0; kk < KC; ++kk) {
        float w = wp[(size_t)kk * N];
        float4 x = *(const float4*)xs[kk];   // broadcast, conflict-free
        a0 = fmaf(x.x, w, a0);
        a1 = fmaf(x.y, w, a1);
        a2 = fmaf(x.z, w, a2);
        a3 = fmaf(x.w, w, a3);
    }
    atomicAdd(&Y[(size_t)(b0 + 0) * N + col], a0);
    atomicAdd(&Y[(size_t)(b0 + 1) * N + col], a1);
    atomicAdd(&Y[(size_t)(b0 + 2) * N + col], a2);
    atomicAdd(&Y[(size_t)(b0 + 3) * N + col], a3);
}

// bias add + RoPE for q,k; bias add for v. One thread per (d, d+64) pair.
__global__ __launch_bounds__(256)
void bias_rope(float* __restrict__ q, float* __restrict__ k, float* __restrict__ v,
               const float* __restrict__ bq, const float* __restrict__ bk,
               const float* __restrict__ bv,
               const float* __restrict__ cosp, const float* __restrict__ sinp) {
    int idx = blockIdx.x * 256 + threadIdx.x;
    if (idx < 32768) {                       // q: 32*16*64 pairs
        int dp = idx & 63;
        int h  = (idx >> 6) & 15;
        int b  = idx >> 10;
        float* qp = q + (size_t)(b * NH + h) * DHD;
        float c0 = cosp[b * DHD + dp],      s0 = sinp[b * DHD + dp];
        float c1 = cosp[b * DHD + dp + 64], s1 = sinp[b * DHD + dp + 64];
        float x0 = qp[dp]      + bq[h * DHD + dp];
        float x1 = qp[dp + 64] + bq[h * DHD + dp + 64];
        qp[dp]      = x0 * c0 - x1 * s0;
        qp[dp + 64] = x1 * c1 + x0 * s1;
    } else if (idx < 32768 + 4096) {         // k: 32*2*64 pairs
        int t  = idx - 32768;
        int dp = t & 63;
        int kh = (t >> 6) & 1;
        int b  = t >> 7;
        float* kp = k + (size_t)(b * NKVH + kh) * DHD;
        float c0 = cosp[b * DHD + dp],      s0 = sinp[b * DHD + dp];
        float c1 = cosp[b * DHD + dp + 64], s1 = sinp[b * DHD + dp + 64];
        float x0 = kp[dp]      + bk[kh * DHD + dp];
        float x1 = kp[dp + 64] + bk[kh * DHD + dp + 64];
        kp[dp]      = x0 * c0 - x1 * s0;
        kp[dp + 64] = x1 * c1 + x0 * s1;
    } else if (idx < 32768 + 4096 + 8192) {  // v bias: 32*2*128
        int t  = idx - 36864;
        int d  = t & 127;
        int kh = (t >> 7) & 1;
        int b  = t >> 8;
        v[(size_t)(b * NKVH + kh) * DHD + d] += bv[kh * DHD + d];
    }
}

// Flash decode. grid = (64 = b*kvh, 8 chunks), block = 256 (8 groups of 32 lanes).
// Each group owns one key per iteration; each lane owns 4 dims; 8 rep-heads at once.
__global__ __launch_bounds__(256)
void attn_decode(const float* __restrict__ pastK, const float* __restrict__ pastV,
                 const float* __restrict__ qbuf, const float* __restrict__ knew,
                 const float* __restrict__ vnew,
                 float* __restrict__ Opart, float* __restrict__ Mpart,
                 float* __restrict__ Lpart) {
    int bk_  = blockIdx.x;
    int b    = bk_ >> 1;
    int kvh  = bk_ & 1;
    int c    = blockIdx.y;
    int g    = threadIdx.x >> 5;
    int lane = threadIdx.x & 31;
    const float scaling = 0.08838834764831845f;  // 128^-0.5

    float4 qf[NREP];
    #pragma unroll
    for (int h = 0; h < NREP; ++h) {
        const float4* qp = (const float4*)(qbuf + (size_t)(b * NH + kvh * NREP + h) * DHD);
        float4 t = qp[lane];
        qf[h] = make_float4(t.x * scaling, t.y * scaling, t.z * scaling, t.w * scaling);
    }
    float  m[NREP], l[NREP];
    float4 acc[NREP];
    #pragma unroll
    for (int h = 0; h < NREP; ++h) {
        m[h] = -1e30f; l[h] = 0.f; acc[h] = make_float4(0.f, 0.f, 0.f, 0.f);
    }

    int nkeys = (c == NCHUNK - 1) ? CHUNK + 1 : CHUNK;
    const float* Kbase = pastK + (size_t)(b * NKVH + kvh) * SPAST * DHD;
    const float* Vbase = pastV + (size_t)(b * NKVH + kvh) * SPAST * DHD;

    for (int i = g; i < nkeys; i += 8) {
        const float4* kp;
        const float4* vp;
        if (i < CHUNK) {
            int key = c * CHUNK + i;
            kp = (const float4*)(Kbase + (size_t)key * DHD);
            vp = (const float4*)(Vbase + (size_t)key * DHD);
        } else {  // the freshly-computed key/value (position 8192)
            kp = (const float4*)(knew + (size_t)(b * NKVH + kvh) * DHD);
            vp = (const float4*)(vnew + (size_t)(b * NKVH + kvh) * DHD);
        }
        float4 k4 = kp[lane];
        float4 v4 = vp[lane];
        float s[NREP];
        #pragma unroll
        for (int h = 0; h < NREP; ++h) {
            s[h] = qf[h].x * k4.x + qf[h].y * k4.y + qf[h].z * k4.z + qf[h].w * k4.w;
        }
        #pragma unroll
        for (int off = 16; off >= 1; off >>= 1) {
            #pragma unroll
            for (int h = 0; h < NREP; ++h) s[h] += __shfl_xor(s[h], off, 32);
        }
        #pragma unroll
        for (int h = 0; h < NREP; ++h) {
            float mo = m[h];
            float mn = fmaxf(mo, s[h]);
            float alpha = __expf(mo - mn);
            float p     = __expf(s[h] - mn);
            m[h] = mn;
            l[h] = l[h] * alpha + p;
            acc[h].x = acc[h].x * alpha + p * v4.x;
            acc[h].y = acc[h].y * alpha + p * v4.y;
            acc[h].z = acc[h].z * alpha + p * v4.z;
            acc[h].w = acc[h].w * alpha + p * v4.w;
        }
    }

    // block combine across the 8 groups
    __shared__ float lm[8][NREP], ll[8][NREP];
    __shared__ __align__(16) float lacc[8][NREP][DHD];
    #pragma unroll
    for (int h = 0; h < NREP; ++h) {
        if (lane == 0) { lm[g][h] = m[h]; ll[g][h] = l[h]; }
        *(float4*)&lacc[g][h][lane * 4] = acc[h];
    }
    __syncthreads();

    int h = g;  // remap: 8 heads x 32 quads = 256 threads
    float mstar = -1e30f;
    #pragma unroll
    for (int gg = 0; gg < 8; ++gg) mstar = fmaxf(mstar, lm[gg][h]);
    float4 O = make_float4(0.f, 0.f, 0.f, 0.f);
    float  L = 0.f;
    #pragma unroll
    for (int gg = 0; gg < 8; ++gg) {
        float f = __expf(lm[gg][h] - mstar);
        L += f * ll[gg][h];
        float4 a = *(const float4*)&lacc[gg][h][lane * 4];
        O.x += f * a.x; O.y += f * a.y; O.z += f * a.z; O.w += f * a.w;
    }
    int gh = kvh * NREP + h;
    float* op = Opart + ((size_t)(b * NH + gh) * NCHUNK + c) * DHD;
    *(float4*)(op + lane * 4) = O;
    if (lane == 0) {
        Mpart[(b * NH + gh) * NCHUNK + c] = mstar;
        Lpart[(b * NH + gh) * NCHUNK + c] = L;
    }
}

__global__ __launch_bounds__(256)
void attn_combine(const float* __restrict__ Opart, const float* __restrict__ Mpart,
                  const float* __restrict__ Lpart, float* __restrict__ attn) {
    int idx  = blockIdx.x * 256 + threadIdx.x;  // 32*16*32 = 16384
    int quad = idx & 31;
    int bh   = idx >> 5;
    float mstar = -1e30f;
    #pragma unroll
    for (int cg = 0; cg < NCHUNK; ++cg) mstar = fmaxf(mstar, Mpart[bh * NCHUNK + cg]);
    float  L = 0.f;
    float4 O = make_float4(0.f, 0.f, 0.f, 0.f);
    #pragma unroll
    for (int cg = 0; cg < NCHUNK; ++cg) {
        float f = __expf(Mpart[bh * NCHUNK + cg] - mstar);
        L += f * Lpart[bh * NCHUNK + cg];
        const float4* ap = (const float4*)(Opart + ((size_t)bh * NCHUNK + cg) * DHD);
        float4 a = ap[quad];
        O.x += f * a.x; O.y += f * a.y; O.z += f * a.z; O.w += f * a.w;
    }
    float inv = 1.0f / L;
    float4* outp = (float4*)(attn + (size_t)bh * DHD);
    outp[quad] = make_float4(O.x * inv, O.y * inv, O.z * inv, O.w * inv);
}

extern "C" void kernel_launch(void* const* d_in, const int* in_sizes, int n_in,
                              void* d_out, int out_size, void* d_ws, size_t ws_size,
                              hipStream_t stream) {
    const float* hs    = (const float*)d_in[0];
    const float* cosp  = (const float*)d_in[1];
    const float* sinp  = (const float*)d_in[2];
    const float* pastK = (const float*)d_in[3];
    const float* pastV = (const float*)d_in[4];
    const float* Wq    = (const float*)d_in[5];
    const float* bq    = (const float*)d_in[6];
    const float* Wk    = (const float*)d_in[7];
    const float* bk    = (const float*)d_in[8];
    const float* Wv    = (const float*)d_in[9];
    const float* bv    = (const float*)d_in[10];
    const float* Wo    = (const float*)d_in[11];
    float* out = (float*)d_out;
    float* ws  = (float*)d_ws;

    float* q     = ws;
    float* k     = ws + 65536;
    float* v     = ws + 73728;
    float* attn  = ws + 81920;
    float* Opart = ws + 147456;
    float* Mpart = ws + 671744;
    float* Lpart = ws + 675840;

    zero_kernel<<<320, 256, 0, stream>>>(ws, out);
    gemm_atomic<<<dim3(8, 8, 4), 256, 0, stream>>>(hs, Wq, q, DD, NH * DHD);
    gemm_atomic<<<dim3(1, 8, 4), 256, 0, stream>>>(hs, Wk, k, DD, NKVH * DHD);
    gemm_atomic<<<dim3(1, 8, 4), 256, 0, stream>>>(hs, Wv, v, DD, NKVH * DHD);
    bias_rope<<<176, 256, 0, stream>>>(q, k, v, bq, bk, bv, cosp, sinp);
    attn_decode<<<dim3(64, 8), 256, 0, stream>>>(pastK, pastV, q, k, v,
                                                 Opart, Mpart, Lpart);
    attn_combine<<<64, 256, 0, stream>>>(Opart, Mpart, Lpart, attn);
    gemm_atomic<<<dim3(8, 8, 4), 256, 0, stream>>>(attn, Wo, out, DD, DD);
}

// Round 2
// 704.118 us; speedup vs baseline: 1.0654x; 1.0654x over previous
//
#include <hip/hip_runtime.h>
#include <math.h>

#define NB 32
#define DD 2048
#define NH 16
#define NKVH 2
#define DHD 128
#define SPAST 8192
#define NREP 8
#define NCHUNK 8
#define CHUNK 1024

// ws layout (float offsets):
// q     : [0, 65536)        [b][h*dh]
// k_new : [65536, 73728)    [b][kvh*dh]
// v_new : [73728, 81920)    [b][kvh*dh]
// attn  : [81920, 147456)   [b][h*dh]
// Opart : [147456, 671744)  [b][h][chunk][d]
// Mpart : [671744, 675840)  [b][h][chunk]
// Lpart : [675840, 679936)  [b][h][chunk]

__global__ __launch_bounds__(256) void zero_kernel(float* ws, float* out) {
    int idx = blockIdx.x * 256 + threadIdx.x;
    if (idx < 81920) ws[idx] = 0.0f;   // q,k,v (atomic targets)
    if (idx < 65536) out[idx] = 0.0f;  // out (atomic target)
}

__device__ inline void resolve_col(int c, const float* Wq, const float* Wk,
                                   const float* Wv, float* q, float* k, float* v,
                                   const float*& w, float*& y, int& n) {
    if (c < 2048)      { w = Wq + c;          y = q + c;          n = 2048; }
    else if (c < 2304) { w = Wk + (c - 2048); y = k + (c - 2048); n = 256;  }
    else               { w = Wv + (c - 2304); y = v + (c - 2304); n = 256;  }
}

// Fused QKV projection. Weights read exactly once.
// grid (5, 32): 512 cols/block (2 per thread), K-chunk 64, all 32 batches.
__global__ __launch_bounds__(256)
void qkv_gemm(const float* __restrict__ X, const float* __restrict__ Wq,
              const float* __restrict__ Wk, const float* __restrict__ Wv,
              float* __restrict__ q, float* __restrict__ k, float* __restrict__ v) {
    int t = threadIdx.x;
    int colbase = blockIdx.x * 512;
    int k0 = blockIdx.y * 64;
    __shared__ __align__(16) float xs[64][36];  // [kk][b], pad 36 vs transpose conflicts
    for (int i = t; i < 2048; i += 256) {
        int kk = i & 63, b = i >> 6;
        xs[kk][b] = X[(size_t)b * DD + k0 + kk];
    }
    __syncthreads();
    int c0 = colbase + t, c1 = colbase + t + 256;
    const float *w0, *w1; float *y0, *y1; int n0, n1;
    resolve_col(c0, Wq, Wk, Wv, q, k, v, w0, y0, n0);
    resolve_col(c1, Wq, Wk, Wv, q, k, v, w1, y1, n1);
    float acc0[32], acc1[32];
    #pragma unroll
    for (int b = 0; b < 32; ++b) { acc0[b] = 0.f; acc1[b] = 0.f; }
    const float* wp0 = w0 + (size_t)k0 * n0;
    const float* wp1 = w1 + (size_t)k0 * n1;
    #pragma unroll 8
    for (int kk = 0; kk < 64; ++kk) {
        float wa = *wp0; wp0 += n0;
        float wb = *wp1; wp1 += n1;
        #pragma unroll
        for (int b4 = 0; b4 < 8; ++b4) {
            float4 x4 = *(const float4*)&xs[kk][b4 * 4];
            acc0[b4*4+0] = fmaf(x4.x, wa, acc0[b4*4+0]);
            acc0[b4*4+1] = fmaf(x4.y, wa, acc0[b4*4+1]);
            acc0[b4*4+2] = fmaf(x4.z, wa, acc0[b4*4+2]);
            acc0[b4*4+3] = fmaf(x4.w, wa, acc0[b4*4+3]);
            acc1[b4*4+0] = fmaf(x4.x, wb, acc1[b4*4+0]);
            acc1[b4*4+1] = fmaf(x4.y, wb, acc1[b4*4+1]);
            acc1[b4*4+2] = fmaf(x4.z, wb, acc1[b4*4+2]);
            acc1[b4*4+3] = fmaf(x4.w, wb, acc1[b4*4+3]);
        }
    }
    #pragma unroll
    for (int b = 0; b < 32; ++b) {
        atomicAdd(&y0[(size_t)b * n0], acc0[b]);
        atomicAdd(&y1[(size_t)b * n1], acc1[b]);
    }
}

// Generic X[32xK] @ W[KxN] += Y, weights read once. grid (N/512, K/64).
__global__ __launch_bounds__(256)
void gemm2(const float* __restrict__ X, const float* __restrict__ W,
           float* __restrict__ Y, int K, int N) {
    int t = threadIdx.x;
    int c0 = blockIdx.x * 512 + t, c1 = c0 + 256;
    int k0 = blockIdx.y * 64;
    __shared__ __align__(16) float xs[64][36];
    for (int i = t; i < 2048; i += 256) {
        int kk = i & 63, b = i >> 6;
        xs[kk][b] = X[(size_t)b * K + k0 + kk];
    }
    __syncthreads();
    float acc0[32], acc1[32];
    #pragma unroll
    for (int b = 0; b < 32; ++b) { acc0[b] = 0.f; acc1[b] = 0.f; }
    const float* wp0 = W + (size_t)k0 * N + c0;
    const float* wp1 = W + (size_t)k0 * N + c1;
    #pragma unroll 8
    for (int kk = 0; kk < 64; ++kk) {
        float wa = *wp0; wp0 += N;
        float wb = *wp1; wp1 += N;
        #pragma unroll
        for (int b4 = 0; b4 < 8; ++b4) {
            float4 x4 = *(const float4*)&xs[kk][b4 * 4];
            acc0[b4*4+0] = fmaf(x4.x, wa, acc0[b4*4+0]);
            acc0[b4*4+1] = fmaf(x4.y, wa, acc0[b4*4+1]);
            acc0[b4*4+2] = fmaf(x4.z, wa, acc0[b4*4+2]);
            acc0[b4*4+3] = fmaf(x4.w, wa, acc0[b4*4+3]);
            acc1[b4*4+0] = fmaf(x4.x, wb, acc1[b4*4+0]);
            acc1[b4*4+1] = fmaf(x4.y, wb, acc1[b4*4+1]);
            acc1[b4*4+2] = fmaf(x4.z, wb, acc1[b4*4+2]);
            acc1[b4*4+3] = fmaf(x4.w, wb, acc1[b4*4+3]);
        }
    }
    #pragma unroll
    for (int b = 0; b < 32; ++b) {
        atomicAdd(&Y[(size_t)b * N + c0], acc0[b]);
        atomicAdd(&Y[(size_t)b * N + c1], acc1[b]);
    }
}

// bias add + RoPE for q,k; bias add for v. One thread per (d, d+64) pair.
__global__ __launch_bounds__(256)
void bias_rope(float* __restrict__ q, float* __restrict__ k, float* __restrict__ v,
               const float* __restrict__ bq, const float* __restrict__ bk,
               const float* __restrict__ bv,
               const float* __restrict__ cosp, const float* __restrict__ sinp) {
    int idx = blockIdx.x * 256 + threadIdx.x;
    if (idx < 32768) {                       // q: 32*16*64 pairs
        int dp = idx & 63;
        int h  = (idx >> 6) & 15;
        int b  = idx >> 10;
        float* qp = q + (size_t)(b * NH + h) * DHD;
        float c0 = cosp[b * DHD + dp],      s0 = sinp[b * DHD + dp];
        float c1 = cosp[b * DHD + dp + 64], s1 = sinp[b * DHD + dp + 64];
        float x0 = qp[dp]      + bq[h * DHD + dp];
        float x1 = qp[dp + 64] + bq[h * DHD + dp + 64];
        qp[dp]      = x0 * c0 - x1 * s0;
        qp[dp + 64] = x1 * c1 + x0 * s1;
    } else if (idx < 32768 + 4096) {         // k: 32*2*64 pairs
        int t  = idx - 32768;
        int dp = t & 63;
        int kh = (t >> 6) & 1;
        int b  = t >> 7;
        float* kp = k + (size_t)(b * NKVH + kh) * DHD;
        float c0 = cosp[b * DHD + dp],      s0 = sinp[b * DHD + dp];
        float c1 = cosp[b * DHD + dp + 64], s1 = sinp[b * DHD + dp + 64];
        float x0 = kp[dp]      + bk[kh * DHD + dp];
        float x1 = kp[dp + 64] + bk[kh * DHD + dp + 64];
        kp[dp]      = x0 * c0 - x1 * s0;
        kp[dp + 64] = x1 * c1 + x0 * s1;
    } else if (idx < 32768 + 4096 + 8192) {  // v bias: 32*2*128
        int t  = idx - 36864;
        int d  = t & 127;
        int kh = (t >> 7) & 1;
        int b  = t >> 8;
        v[(size_t)(b * NKVH + kh) * DHD + d] += bv[kh * DHD + d];
    }
}

// Flash decode v2: no per-key shuffles.
// grid (64, 8 chunks), block 256. Phase 1: lane-per-key scores (4 keys/thread),
// q broadcast from LDS. One softmax reduction per chunk. Phase 2: P*V with
// threads = (head, dim-quad), V rows coalesced, P broadcast from LDS.
__global__ __launch_bounds__(256)
void attn_decode(const float* __restrict__ pastK, const float* __restrict__ pastV,
                 const float* __restrict__ qbuf, const float* __restrict__ knew,
                 const float* __restrict__ vnew,
                 float* __restrict__ Opart, float* __restrict__ Mpart,
                 float* __restrict__ Lpart) {
    int b    = blockIdx.x >> 1;
    int kvh  = blockIdx.x & 1;
    int c    = blockIdx.y;
    int t    = threadIdx.x;
    int lane = t & 63;
    int wid  = t >> 6;
    const float scaling = 0.08838834764831845f;  // 128^-0.5

    __shared__ __align__(16) float qs[NREP][DHD];        // 4 KB
    __shared__ float ptile[NREP][CHUNK + 8];             // 33 KB (slot 1024 = new key)
    __shared__ float redm[4][NREP], redl[4][NREP];
    __shared__ float snew_s[NREP];

    for (int i = t; i < NREP * DHD; i += 256) {
        int h = i >> 7, d = i & 127;
        qs[h][d] = qbuf[((size_t)(b * NH) + kvh * NREP + h) * DHD + d] * scaling;
    }
    __syncthreads();

    // ---- Phase 1: scores. Thread t owns keys c*1024 + t + 256j, j=0..3.
    const float* Kbase = pastK + ((size_t)(b * NKVH) + kvh) * SPAST * DHD;
    const float4* kp[4];
    #pragma unroll
    for (int j = 0; j < 4; ++j)
        kp[j] = (const float4*)(Kbase + (size_t)(c * CHUNK + t + 256 * j) * DHD);
    float s[4][8];
    #pragma unroll
    for (int j = 0; j < 4; ++j)
        #pragma unroll
        for (int h = 0; h < 8; ++h) s[j][h] = 0.f;

    #pragma unroll 2
    for (int c4 = 0; c4 < 32; ++c4) {
        float4 kr[4];
        #pragma unroll
        for (int j = 0; j < 4; ++j) kr[j] = kp[j][c4];
        #pragma unroll
        for (int h = 0; h < 8; ++h) {
            float4 q4 = *(const float4*)&qs[h][c4 * 4];
            #pragma unroll
            for (int j = 0; j < 4; ++j) {
                s[j][h] = fmaf(q4.x, kr[j].x, s[j][h]);
                s[j][h] = fmaf(q4.y, kr[j].y, s[j][h]);
                s[j][h] = fmaf(q4.z, kr[j].z, s[j][h]);
                s[j][h] = fmaf(q4.w, kr[j].w, s[j][h]);
            }
        }
    }

    // new key (position 8192): only last chunk, computed by threads 0..7
    if (c == NCHUNK - 1 && t < 8) {
        const float4* kn = (const float4*)(knew + (size_t)(b * NKVH + kvh) * DHD);
        float sa = 0.f;
        for (int c4 = 0; c4 < 32; ++c4) {
            float4 q4 = *(const float4*)&qs[t][c4 * 4];
            float4 k4 = kn[c4];
            sa += q4.x * k4.x + q4.y * k4.y + q4.z * k4.z + q4.w * k4.w;
        }
        snew_s[t] = sa;
    }

    // per-head max: thread-local -> wave shuffle -> LDS cross-wave
    float mm[8];
    #pragma unroll
    for (int h = 0; h < 8; ++h)
        mm[h] = fmaxf(fmaxf(s[0][h], s[1][h]), fmaxf(s[2][h], s[3][h]));
    #pragma unroll
    for (int off = 32; off >= 1; off >>= 1)
        #pragma unroll
        for (int h = 0; h < 8; ++h) mm[h] = fmaxf(mm[h], __shfl_xor(mm[h], off));
    if (lane == 0)
        #pragma unroll
        for (int h = 0; h < 8; ++h) redm[wid][h] = mm[h];
    __syncthreads();

    float m[8];
    #pragma unroll
    for (int h = 0; h < 8; ++h) {
        m[h] = fmaxf(fmaxf(redm[0][h], redm[1][h]), fmaxf(redm[2][h], redm[3][h]));
        if (c == NCHUNK - 1) m[h] = fmaxf(m[h], snew_s[h]);
    }

    // p = exp(s - m), write to ptile, accumulate l
    float ll[8];
    #pragma unroll
    for (int h = 0; h < 8; ++h) ll[h] = 0.f;
    #pragma unroll
    for (int j = 0; j < 4; ++j)
        #pragma unroll
        for (int h = 0; h < 8; ++h) {
            float p = __expf(s[j][h] - m[h]);
            ptile[h][t + 256 * j] = p;
            ll[h] += p;
        }
    #pragma unroll
    for (int off = 32; off >= 1; off >>= 1)
        #pragma unroll
        for (int h = 0; h < 8; ++h) ll[h] += __shfl_xor(ll[h], off);
    if (lane == 0)
        #pragma unroll
        for (int h = 0; h < 8; ++h) redl[wid][h] = ll[h];
    __syncthreads();

    if (t < 8) {
        int h = t;
        float L = redl[0][h] + redl[1][h] + redl[2][h] + redl[3][h];
        if (c == NCHUNK - 1) {
            float pn = __expf(snew_s[h] - m[h]);
            ptile[h][CHUNK] = pn;
            L += pn;
        }
        int gh = kvh * NREP + h;
        Mpart[(b * NH + gh) * NCHUNK + c] = m[h];
        Lpart[(b * NH + gh) * NCHUNK + c] = L;
    }
    __syncthreads();

    // ---- Phase 2: P*V. thread = (head t>>5, quad t&31)
    int h2   = t >> 5;
    int quad = t & 31;
    const float* Vrow0 = pastV + (((size_t)(b * NKVH) + kvh) * SPAST + c * CHUNK) * DHD;
    float4 a = make_float4(0.f, 0.f, 0.f, 0.f);
    #pragma unroll 8
    for (int kk = 0; kk < CHUNK; ++kk) {
        float p = ptile[h2][kk];
        float4 v4 = *(const float4*)(Vrow0 + (size_t)kk * DHD + quad * 4);
        a.x = fmaf(p, v4.x, a.x);
        a.y = fmaf(p, v4.y, a.y);
        a.z = fmaf(p, v4.z, a.z);
        a.w = fmaf(p, v4.w, a.w);
    }
    if (c == NCHUNK - 1) {
        float p = ptile[h2][CHUNK];
        float4 v4 = *(const float4*)(vnew + (size_t)(b * NKVH + kvh) * DHD + quad * 4);
        a.x = fmaf(p, v4.x, a.x);
        a.y = fmaf(p, v4.y, a.y);
        a.z = fmaf(p, v4.z, a.z);
        a.w = fmaf(p, v4.w, a.w);
    }
    int gh = kvh * NREP + h2;
    float* op = Opart + ((size_t)(b * NH + gh) * NCHUNK + c) * DHD;
    *(float4*)(op + quad * 4) = a;
}

__global__ __launch_bounds__(256)
void attn_combine(const float* __restrict__ Opart, const float* __restrict__ Mpart,
                  const float* __restrict__ Lpart, float* __restrict__ attn) {
    int idx  = blockIdx.x * 256 + threadIdx.x;  // 32*16*32 = 16384
    int quad = idx & 31;
    int bh   = idx >> 5;
    float mstar = -1e30f;
    #pragma unroll
    for (int cg = 0; cg < NCHUNK; ++cg) mstar = fmaxf(mstar, Mpart[bh * NCHUNK + cg]);
    float  L = 0.f;
    float4 O = make_float4(0.f, 0.f, 0.f, 0.f);
    #pragma unroll
    for (int cg = 0; cg < NCHUNK; ++cg) {
        float f = __expf(Mpart[bh * NCHUNK + cg] - mstar);
        L += f * Lpart[bh * NCHUNK + cg];
        const float4* ap = (const float4*)(Opart + ((size_t)bh * NCHUNK + cg) * DHD);
        float4 a = ap[quad];
        O.x += f * a.x; O.y += f * a.y; O.z += f * a.z; O.w += f * a.w;
    }
    float inv = 1.0f / L;
    float4* outp = (float4*)(attn + (size_t)bh * DHD);
    outp[quad] = make_float4(O.x * inv, O.y * inv, O.z * inv, O.w * inv);
}

extern "C" void kernel_launch(void* const* d_in, const int* in_sizes, int n_in,
                              void* d_out, int out_size, void* d_ws, size_t ws_size,
                              hipStream_t stream) {
    const float* hs    = (const float*)d_in[0];
    const float* cosp  = (const float*)d_in[1];
    const float* sinp  = (const float*)d_in[2];
    const float* pastK = (const float*)d_in[3];
    const float* pastV = (const float*)d_in[4];
    const float* Wq    = (const float*)d_in[5];
    const float* bq    = (const float*)d_in[6];
    const float* Wk    = (const float*)d_in[7];
    const float* bk    = (const float*)d_in[8];
    const float* Wv    = (const float*)d_in[9];
    const float* bv    = (const float*)d_in[10];
    const float* Wo    = (const float*)d_in[11];
    float* out = (float*)d_out;
    float* ws  = (float*)d_ws;

    float* q     = ws;
    float* k     = ws + 65536;
    float* v     = ws + 73728;
    float* attn  = ws + 81920;
    float* Opart = ws + 147456;
    float* Mpart = ws + 671744;
    float* Lpart = ws + 675840;

    zero_kernel<<<320, 256, 0, stream>>>(ws, out);
    qkv_gemm<<<dim3(5, 32), 256, 0, stream>>>(hs, Wq, Wk, Wv, q, k, v);
    bias_rope<<<176, 256, 0, stream>>>(q, k, v, bq, bk, bv, cosp, sinp);
    attn_decode<<<dim3(64, 8), 256, 0, stream>>>(pastK, pastV, q, k, v,
                                                 Opart, Mpart, Lpart);
    attn_combine<<<64, 256, 0, stream>>>(Opart, Mpart, Lpart, attn);
    gemm2<<<dim3(4, 32), 256, 0, stream>>>(attn, Wo, out, DD, DD);
}